// Round 5
// baseline (196.662 us; speedup 1.0000x reference)
//
#include <hip/hip_runtime.h>

#define LAT_SHAPE 1801
#define LON_SHAPE 3600
#define NPTS 2000000

__global__ __launch_bounds__(256) void le_kernel(
    const float2* __restrict__ x,
    const float* __restrict__ g0, const float* __restrict__ g1,
    const float* __restrict__ g2, const float* __restrict__ g3,
    const float* __restrict__ g4, const float* __restrict__ g5,
    const float* __restrict__ g6, const float* __restrict__ g7,
    float* __restrict__ out, int n)
{
#pragma clang fp contract(off)
    int idx = blockIdx.x * blockDim.x + threadIdx.x;
    if (idx >= n) return;

    float2 p = x[idx];
    float lat = p.x;
    float lon = p.y;

    // coord2index via MULTIPLICATION by 10 (the natural hand-written form for
    // a 0.1-degree grid), f32, ties-even (np.round). x*10f vs x/0.1f differ by
    // ~1.5e-8 rel -> ~160 of 2M points round differently: the stable wrong-set
    // signature seen across all four division-based kernels.
    float qy = (90.0f - lat) * 10.0f;
    float qx = lon * 10.0f;
    int yi = (int)rintf(qy);
    int xi = (int)rintf(qx);
    yi = min(max(yi, 0), LAT_SHAPE - 1);
    xi = min(max(xi, 0), LON_SHAPE - 1);

    float res[8];

    // Level 0: Hin == Hout -> scale exactly 1.0, sy == yi, weights 0:
    // blend collapses to v00 exactly. Single gather.
    res[0] = g0[yi * LON_SHAPE + xi];

    const float* gs[8] = {g0, g1, g2, g3, g4, g5, g6, g7};
    constexpr int H[8] = {1801, 901, 451, 226, 113, 57, 29, 15};
    constexpr int W[8] = {3600, 1800, 900, 450, 225, 113, 57, 29};

    const float yif = (float)yi;
    const float xif = (float)xi;

#pragma unroll
    for (int i = 1; i < 8; ++i) {
        // scale = f32(Hin/Hout): python f64 ratio cast to f32 (NEP50 weak promo)
        const float sy_scale = (float)((double)H[i] / (double)LAT_SHAPE);
        const float sx_scale = (float)((double)W[i] / (double)LON_SHAPE);

        float sy = fmaxf((yif + 0.5f) * sy_scale - 0.5f, 0.0f);
        float sx = fmaxf((xif + 0.5f) * sx_scale - 0.5f, 0.0f);

        int y0 = (int)sy;   // floor: sy >= 0
        int x0 = (int)sx;
        float wy = sy - (float)y0;
        float wx = sx - (float)x0;
        int y1 = min(y0 + 1, H[i] - 1);
        int x1 = min(x0 + 1, W[i] - 1);

        const float* __restrict__ g = gs[i];
        float v00 = g[y0 * W[i] + x0];
        float v01 = g[y0 * W[i] + x1];
        float v10 = g[y1 * W[i] + x0];
        float v11 = g[y1 * W[i] + x1];

        // Exact mirror of the reference blend (continuous; fp noise ~1e-7)
        float omwy = 1.0f - wy, omwx = 1.0f - wx;
        res[i] = v00 * omwy * omwx + v01 * omwy * wx
               + v10 * wy * omwx + v11 * wy * wx;
    }

    float4* o = (float4*)(out + (size_t)idx * 8);
    o[0] = make_float4(res[0], res[1], res[2], res[3]);
    o[1] = make_float4(res[4], res[5], res[6], res[7]);
}

extern "C" void kernel_launch(void* const* d_in, const int* in_sizes, int n_in,
                              void* d_out, int out_size, void* d_ws, size_t ws_size,
                              hipStream_t stream) {
    // Assign roles by unique element count (verified equivalent to positional
    // in earlier rounds; kept for robustness).
    const int GSZ[8] = {6483600, 1621800, 405900, 101700, 25425, 6441, 1653, 435};
    const float* xp = nullptr;
    const float* g[8] = {nullptr};
    int n = 0;
    for (int i = 0; i < n_in; ++i) {
        int s = in_sizes[i];
        if (s == 2 * NPTS) { xp = (const float*)d_in[i]; n = NPTS; continue; }
        for (int l = 0; l < 8; ++l)
            if (s == GSZ[l]) { g[l] = (const float*)d_in[i]; break; }
    }
    if (!xp) { xp = (const float*)d_in[0]; n = in_sizes[0] / 2; }
    for (int l = 0; l < 8; ++l)
        if (!g[l]) g[l] = (const float*)d_in[1 + l];

    int blocks = (n + 255) / 256;
    le_kernel<<<blocks, 256, 0, stream>>>((const float2*)xp, g[0], g[1], g[2],
                                          g[3], g[4], g[5], g[6], g[7],
                                          (float*)d_out, n);
}

// Round 7
// 145.311 us; speedup vs baseline: 1.3534x; 1.3534x over previous
//
#include <hip/hip_runtime.h>

#define LAT_SHAPE 1801
#define LON_SHAPE 3600
#define NPTS 2000000

typedef float f32x4 __attribute__((ext_vector_type(4)));

__global__ __launch_bounds__(256) void le_kernel(
    const float2* __restrict__ x,
    const float* __restrict__ g0, const float* __restrict__ g1,
    const float* __restrict__ g2, const float* __restrict__ g3,
    const float* __restrict__ g4, const float* __restrict__ g5,
    const float* __restrict__ g6, const float* __restrict__ g7,
    float* __restrict__ out, int n)
{
#pragma clang fp contract(off)
    // LDS: levels 6-7 grids (8.3KB) + output packing buffer (8KB) = 16.4KB
    // -> 8 blocks/CU (wave-limited), full 32 waves/CU occupancy retained.
    __shared__ float g6s[1653];   // 29 x 57
    __shared__ float g7s[435];    // 15 x 29
    __shared__ f32x4 obuf[512];

    for (int k = threadIdx.x; k < 1653; k += 256) g6s[k] = g6[k];
    for (int k = threadIdx.x; k < 435; k += 256) g7s[k] = g7[k];
    __syncthreads();

    int idx = blockIdx.x * blockDim.x + threadIdx.x;
    int cidx = min(idx, n - 1);   // tail threads duplicate last point; their
                                  // results land in guarded obuf slots only.

    float2 p = x[cidx];
    float lat = p.x;
    float lon = p.y;

    // FROZEN MATH (bit-exact vs np golden, round 5): f32, *10.0f, ties-even.
    float qy = (90.0f - lat) * 10.0f;
    float qx = lon * 10.0f;
    int yi = (int)rintf(qy);
    int xi = (int)rintf(qx);
    yi = min(max(yi, 0), LAT_SHAPE - 1);
    xi = min(max(xi, 0), LON_SHAPE - 1);

    float res[8];

    // Level 0: scale exactly 1.0 -> blend collapses to v00. Single gather.
    res[0] = g0[yi * LON_SHAPE + xi];

    constexpr int H[8] = {1801, 901, 451, 226, 113, 57, 29, 15};
    constexpr int W[8] = {3600, 1800, 900, 450, 225, 113, 57, 29};

    const float yif = (float)yi;
    const float xif = (float)xi;

    // Generic lambda keeps pointer provenance (global vs LDS) per call site.
    auto bilin = [&](auto g, int Hi, int Wi, float sy_scale, float sx_scale) -> float {
#pragma clang fp contract(off)
        float sy = fmaxf((yif + 0.5f) * sy_scale - 0.5f, 0.0f);
        float sx = fmaxf((xif + 0.5f) * sx_scale - 0.5f, 0.0f);
        int y0 = (int)sy;   // floor: sy >= 0
        int x0 = (int)sx;
        float wy = sy - (float)y0;
        float wx = sx - (float)x0;
        int y1 = min(y0 + 1, Hi - 1);
        int x1 = min(x0 + 1, Wi - 1);
        float v00 = g[y0 * Wi + x0];
        float v01 = g[y0 * Wi + x1];
        float v10 = g[y1 * Wi + x0];
        float v11 = g[y1 * Wi + x1];
        float omwy = 1.0f - wy, omwx = 1.0f - wx;
        return v00 * omwy * omwx + v01 * omwy * wx
             + v10 * wy * omwx + v11 * wy * wx;
    };

#define SC(i, dim, tot) ((float)((double)dim[i] / (double)tot))
    res[1] = bilin(g1, H[1], W[1], SC(1, H, LAT_SHAPE), SC(1, W, LON_SHAPE));
    res[2] = bilin(g2, H[2], W[2], SC(2, H, LAT_SHAPE), SC(2, W, LON_SHAPE));
    res[3] = bilin(g3, H[3], W[3], SC(3, H, LAT_SHAPE), SC(3, W, LON_SHAPE));
    res[4] = bilin(g4, H[4], W[4], SC(4, H, LAT_SHAPE), SC(4, W, LON_SHAPE));
    res[5] = bilin(g5, H[5], W[5], SC(5, H, LAT_SHAPE), SC(5, W, LON_SHAPE));
    res[6] = bilin((const float*)g6s, H[6], W[6], SC(6, H, LAT_SHAPE), SC(6, W, LON_SHAPE));
    res[7] = bilin((const float*)g7s, H[7], W[7], SC(7, H, LAT_SHAPE), SC(7, W, LON_SHAPE));
#undef SC

    // Pack 8 floats/point through LDS so each store instruction covers a
    // fully-contiguous 1KB range (fixes the 2x WRITE_SIZE partial-granule
    // anomaly). obuf[2p+h] = half h of local point p.
    f32x4 lo = {res[0], res[1], res[2], res[3]};
    f32x4 hi = {res[4], res[5], res[6], res[7]};
    obuf[2 * threadIdx.x]     = lo;
    obuf[2 * threadIdx.x + 1] = hi;
    __syncthreads();

    const size_t total_f4 = (size_t)n * 2;
    const size_t base = (size_t)blockIdx.x * 512;
    f32x4* o4 = (f32x4*)out;
    int t = threadIdx.x;
    if (base + t < total_f4)
        __builtin_nontemporal_store(obuf[t], &o4[base + t]);
    if (base + 256 + t < total_f4)
        __builtin_nontemporal_store(obuf[256 + t], &o4[base + 256 + t]);
}

extern "C" void kernel_launch(void* const* d_in, const int* in_sizes, int n_in,
                              void* d_out, int out_size, void* d_ws, size_t ws_size,
                              hipStream_t stream) {
    // Assign roles by unique element count (robust to input permutation).
    const int GSZ[8] = {6483600, 1621800, 405900, 101700, 25425, 6441, 1653, 435};
    const float* xp = nullptr;
    const float* g[8] = {nullptr};
    int n = 0;
    for (int i = 0; i < n_in; ++i) {
        int s = in_sizes[i];
        if (s == 2 * NPTS) { xp = (const float*)d_in[i]; n = NPTS; continue; }
        for (int l = 0; l < 8; ++l)
            if (s == GSZ[l]) { g[l] = (const float*)d_in[i]; break; }
    }
    if (!xp) { xp = (const float*)d_in[0]; n = in_sizes[0] / 2; }
    for (int l = 0; l < 8; ++l)
        if (!g[l]) g[l] = (const float*)d_in[1 + l];

    int blocks = (n + 255) / 256;
    le_kernel<<<blocks, 256, 0, stream>>>((const float2*)xp, g[0], g[1], g[2],
                                          g[3], g[4], g[5], g[6], g[7],
                                          (float*)d_out, n);
}